// Round 6
// baseline (150.443 us; speedup 1.0000x reference)
//
#include <hip/hip_runtime.h>
#include <math.h>

#define BSZ 65536
#define NC 10
#define T 8
#define NE 128
#define EMB 256
#define ZD 128
#define NCT 80
#define CCF 0.25f
#define BB 32

// ws float offsets
#define WT_OFF  0        // Wt[80][128] fp32, k-major
#define B2_OFF  10240    // 128 fused bias
#define CT_OFF  11904    // 128 u32 histogram
#define SQ_OFF  12032    // 1 float sq-err accumulator
#define AH_OFF  12288    // 2048 floats = 4096 halves: MFMA A-frag table [8][64] half8
#define G_OFF   16384    // G[8][128][128] fp32 gather table (512 KB)

typedef _Float16 half8 __attribute__((ext_vector_type(8)));
typedef float f32x4 __attribute__((ext_vector_type(4)));

// ---------------------------------------------------------------------------
// prep1: Wt = (mu_w@fc_w)^T; b2 = mu_w@fc_b + mu_b; zeros; MFMA A-frag table.
// A-slot layout (K=32): 0-9=-ch, 10-19=-cl, 20-29=-ch, 30=cn/2 hi, 31=cn/2 lo.
// Entry id within a 16-tile: entry = nt*16 + reg*4 + quad, so A row
// m=quad*4+reg holds codebook entry nt*16 + (m&3)*4 + (m>>2).
// ---------------------------------------------------------------------------
__global__ __launch_bounds__(256) void prep1_kernel(
    const float* __restrict__ codebook, const float* __restrict__ fc_w,
    const float* __restrict__ fc_b, const float* __restrict__ mu_w,
    const float* __restrict__ mu_b, float* __restrict__ ws)
{
  const int blk = blockIdx.x, tid = threadIdx.x;
  if (blk < 80) {                       // W = mu_w@fc_w, transposed store
    const int gi = blk * 256 + tid;
    const int idx = gi >> 1, h = gi & 1;
    const int d = idx / NCT, k = idx - d * NCT;
    const float* mw = mu_w + d * EMB + h * 128;
    const float* fw = fc_w + (h * 128) * NCT + k;
    float acc = 0.f;
#pragma unroll 8
    for (int e = 0; e < 128; ++e) acc = fmaf(mw[e], fw[e * NCT], acc);
    acc += __shfl_xor(acc, 1);
    if (h == 0) ws[WT_OFF + k * 128 + d] = acc;
  } else if (blk == 80) {               // b2
    const int d = tid >> 1, h = tid & 1;
    const float* mw = mu_w + d * EMB + h * 128;
    const float* fb = fc_b + h * 128;
    float acc = 0.f;
#pragma unroll 8
    for (int e = 0; e < 128; ++e) acc = fmaf(mw[e], fb[e], acc);
    acc += __shfl_xor(acc, 1);
    if (h == 0) ws[B2_OFF + d] = acc + mu_b[d];
  } else if (blk == 81) {               // zero accumulators
    if (tid < NE) ((unsigned*)ws)[CT_OFF + tid] = 0u;
    if (tid == 0) ws[SQ_OFF] = 0.f;
  } else {                              // blk 82/83: A-frag tables
    const int nt = (blk - 82) * 4 + (tid >> 6);
    const int lane = tid & 63;
    const int rl = lane & 15, q = lane >> 4;
    const int X = nt * 16 + ((rl & 3) << 2) + (rl >> 2);
    float cb_[NC]; float cn = 0.f;
#pragma unroll
    for (int c = 0; c < NC; ++c) { cb_[c] = codebook[X * NC + c]; cn = fmaf(cb_[c], cb_[c], cn); }
    const float cn2 = 0.5f * cn;
    const _Float16 cnh = (_Float16)cn2;
    const _Float16 cnl = (_Float16)(cn2 - (float)cnh);
    half8 hv;
#pragma unroll
    for (int j = 0; j < 8; ++j) {
      const int s = q * 8 + j;
      _Float16 val;
      if (s < 10) {
        val = (_Float16)(-cb_[s]);
      } else if (s < 20) {
        float m = -cb_[s - 10];
        _Float16 mh = (_Float16)m;
        val = (_Float16)(m - (float)mh);
      } else if (s < 30) {
        val = (_Float16)(-cb_[s - 20]);
      } else if (s == 30) val = cnh; else val = cnl;
      hv[j] = val;
    }
    ((half8*)(ws + AH_OFF))[nt * 64 + lane] = hv;
  }
}

// ---------------------------------------------------------------------------
// prep2: G[t][e][d] = sum_c cb[e][c] * W[d][c*8+t]
// ---------------------------------------------------------------------------
__global__ __launch_bounds__(128) void prep2_kernel(
    const float* __restrict__ codebook, float* __restrict__ ws)
{
  const int t = blockIdx.x >> 7, e = blockIdx.x & 127, d = threadIdx.x;
  float acc = 0.f;
#pragma unroll
  for (int c = 0; c < NC; ++c)
    acc = fmaf(codebook[e * NC + c], ws[WT_OFF + (c * 8 + t) * 128 + d], acc);
  ws[G_OFF + ((t * 128 + e) << 7) + d] = acc;
}

// ---------------------------------------------------------------------------
// main: conv -> transposed-MFMA distances -> lane-local u32-key top-2 ->
// rare fp64 pair recheck (global codebook) -> G-table gather.
// Hot path entirely wave-local; 2 barriers total; LDS ~19 KB conflict-free.
// ---------------------------------------------------------------------------
__global__ __launch_bounds__(256, 8) void main_kernel(
    const float* __restrict__ fn, const unsigned char* __restrict__ mask,
    const float* __restrict__ conv_w, const float* __restrict__ conv_b,
    const float* __restrict__ codebook, float* __restrict__ ws,
    float* __restrict__ out)
{
  __shared__ __align__(16) _Float16 zB[4 * 256 * 8];  // [slot_q][pos] half8, 16 KB
  __shared__ uint2 kres[256];                         // 2 KB
  __shared__ unsigned hist[NE];                       // 512 B
  __shared__ float sqacc;

  const int tid = threadIdx.x;
  const int lane = tid & 63, w = tid >> 6;
  const int rl = lane & 15, qd = lane >> 4;

  if (tid < NE) hist[tid] = 0u;
  if (tid == 255) sqacc = 0.f;
  __syncthreads();                      // barrier 1: hist/sqacc ready

  // ---- A-frag preload (global, L2-hot) ----
  const half8* ahp = (const half8*)(ws + AH_OFF);
  half8 A[8];
#pragma unroll
  for (int nt = 0; nt < 8; ++nt) A[nt] = ahp[nt * 64 + lane];

  // ---- conv, one (b,t) per thread ----
  const float4 pv = ((const float4*)fn)[blockIdx.x * 256 + tid];
  float z[NC];
#pragma unroll
  for (int c = 0; c < NC; ++c) {
    float pre = fmaf(pv.w, conv_w[c * 4 + 3], fmaf(pv.z, conv_w[c * 4 + 2],
                fmaf(pv.y, conv_w[c * 4 + 1], fmaf(pv.x, conv_w[c * 4 + 0], conv_b[c]))));
    z[c] = pre > 0.f ? pre : 0.f;
  }
  float zn = 0.f;
#pragma unroll
  for (int c = 0; c < NC; ++c) zn = fmaf(z[c], z[c], zn);
  const float zkey = fmaf(0.5f, zn, 1.0f);   // +1 bias keeps keys positive

  // split z to f16 hi/lo; pack B-vector slots: 0-9=zh, 10-19=zh, 20-29=zl, 30,31=1
  _Float16 zh[NC], zl[NC];
#pragma unroll
  for (int c = 0; c < NC; ++c) {
    zh[c] = (_Float16)z[c];
    zl[c] = (_Float16)(z[c] - (float)zh[c]);
  }
  {
    half8* zb = (half8*)zB;
    zb[0 * 256 + tid] = (half8){zh[0], zh[1], zh[2], zh[3], zh[4], zh[5], zh[6], zh[7]};
    zb[1 * 256 + tid] = (half8){zh[8], zh[9], zh[0], zh[1], zh[2], zh[3], zh[4], zh[5]};
    zb[2 * 256 + tid] = (half8){zh[6], zh[7], zh[8], zh[9], zl[0], zl[1], zl[2], zl[3]};
    zb[3 * 256 + tid] = (half8){zl[4], zl[5], zl[6], zl[7], zl[8], zl[9],
                                (_Float16)1.f, (_Float16)1.f};
  }

  // ---- MFMA distance + lane-local top-2 keys (all wave-local) ----
  for (int mt = 0; mt < 4; ++mt) {
    const int pos = mt * 16 + rl;            // wave-relative position
    const int wpos = w * 64 + pos;
    const half8 bf = ((const half8*)zB)[qd * 256 + wpos];
    const float zn2 = __shfl(zkey, pos);     // owner is lane `pos` of this wave
    const f32x4 cinit = {zn2, zn2, zn2, zn2};
    unsigned b1 = 0xFFFFFFFFu, b2 = 0xFFFFFFFFu;
#pragma unroll
    for (int nt = 0; nt < 8; ++nt) {
      const f32x4 acc = __builtin_amdgcn_mfma_f32_16x16x32_f16(A[nt], bf, cinit, 0, 0, 0);
#pragma unroll
      for (int reg = 0; reg < 4; ++reg) {
        const unsigned u = __float_as_uint(acc[reg]);
        const unsigned key = ((u & 0xFFFFFF80u) | (unsigned)qd) + (unsigned)(nt * 16 + reg * 4);
        const unsigned t = b1 > key ? b1 : key;
        b1 = b1 < key ? b1 : key;
        b2 = b2 < t ? b2 : t;
      }
    }
#pragma unroll
    for (int s = 16; s <= 32; s <<= 1) {     // cross-quad top-2 merge
      const unsigned o1 = (unsigned)__shfl_xor((int)b1, s);
      const unsigned o2 = (unsigned)__shfl_xor((int)b2, s);
      const unsigned t = b1 > o1 ? b1 : o1;
      b1 = b1 < o1 ? b1 : o1;
      b2 = b2 < o2 ? b2 : o2;
      b2 = b2 < t ? b2 : t;
    }
    if (lane < 16) kres[wpos] = make_uint2(b1, b2);
  }

  // ---- owner finalize (wave-local kres) ----
  const uint2 kk = kres[tid];
  int bi = (int)(kk.x & 127u);
  const float v1 = __uint_as_float(kk.x & 0xFFFFFF80u);
  float vsel = v1;
  {
    const float v2 = __uint_as_float(kk.y & 0xFFFFFF80u);
    if (v2 - v1 < fmaf(1e-4f, v1, 2e-4f)) {  // near-tie: rare fp64 pair recheck
      const int bi2 = (int)(kk.y & 127u);
      double s1 = 0.0, s2 = 0.0;
      for (int c = 0; c < NC; ++c) {
        double a = (double)z[c] - (double)codebook[bi * NC + c];
        double q2 = (double)z[c] - (double)codebook[bi2 * NC + c];
        s1 += a * a; s2 += q2 * q2;
      }
      if (s2 < s1 || (s2 == s1 && bi2 < bi)) { bi = bi2; vsel = v2; }
    }
  }
  // sq err recovered from key: key value = 1 + ||z-c||^2 / 2
  float sq = 2.0f * (vsel - 1.0f);
  sq = sq > 0.f ? sq : 0.f;

  const int bg = blockIdx.x * BB + (tid >> 3);
  const bool valid = (mask[bg] == 0);
  float sv = valid ? sq : 0.f;
#pragma unroll
  for (int off = 32; off > 0; off >>= 1) sv += __shfl_down(sv, off);
  if (lane == 0) atomicAdd(&sqacc, sv);
  if (valid) atomicAdd(&hist[bi], 1u);

  // ---- stage 3: out[b][:] = b2 + sum_t G[t][idx[b,t]][:] (indices via shfl) ----
  const int b_loc = tid >> 3, dc = tid & 7;
  const int obase = lane & ~7;               // wave-relative owner base
  int idx8[8];
#pragma unroll
  for (int t = 0; t < 8; ++t) idx8[t] = __shfl(bi, obase + t);

  float4 a0 = {0, 0, 0, 0}, a1 = {0, 0, 0, 0}, a2 = {0, 0, 0, 0}, a3 = {0, 0, 0, 0};
#pragma unroll
  for (int t = 0; t < 8; ++t) {
    const float4* gp = (const float4*)&ws[G_OFF + ((t * 128 + idx8[t]) << 7)];
    const float4 g0 = gp[0 * 8 + dc], g1 = gp[1 * 8 + dc];
    const float4 g2 = gp[2 * 8 + dc], g3 = gp[3 * 8 + dc];
    a0.x += g0.x; a0.y += g0.y; a0.z += g0.z; a0.w += g0.w;
    a1.x += g1.x; a1.y += g1.y; a1.z += g1.z; a1.w += g1.w;
    a2.x += g2.x; a2.y += g2.y; a2.z += g2.z; a2.w += g2.w;
    a3.x += g3.x; a3.y += g3.y; a3.z += g3.z; a3.w += g3.w;
  }
  {
    const float4* bp = (const float4*)&ws[B2_OFF];
    const float4 b0 = bp[0 * 8 + dc], b1v = bp[1 * 8 + dc];
    const float4 b2v = bp[2 * 8 + dc], b3 = bp[3 * 8 + dc];
    a0.x += b0.x; a0.y += b0.y; a0.z += b0.z; a0.w += b0.w;
    a1.x += b1v.x; a1.y += b1v.y; a1.z += b1v.z; a1.w += b1v.w;
    a2.x += b2v.x; a2.y += b2v.y; a2.z += b2v.z; a2.w += b2v.w;
    a3.x += b3.x; a3.y += b3.y; a3.z += b3.z; a3.w += b3.w;
    float4* op = (float4*)&out[(size_t)(blockIdx.x * BB + b_loc) * ZD];
    op[0 * 8 + dc] = a0; op[1 * 8 + dc] = a1; op[2 * 8 + dc] = a2; op[3 * 8 + dc] = a3;
  }

  // ---- global accumulation ----
  __syncthreads();                      // barrier 2: all atomics done
  if (tid == 0) atomicAdd(&ws[SQ_OFF], sqacc);
  if (tid < NE) { unsigned h = hist[tid]; if (h) atomicAdd(&((unsigned*)ws)[CT_OFF + tid], h); }
}

// ---------------------------------------------------------------------------
// fin: cmt_loss and perplexity.
// ---------------------------------------------------------------------------
__global__ __launch_bounds__(128) void fin_kernel(const float* __restrict__ ws,
                                                  float* __restrict__ out)
{
  __shared__ float red[NE];
  const int tid = threadIdx.x;
  const unsigned c = ((const unsigned*)ws)[CT_OFF + tid];
  const float cf = (float)c;
  red[tid] = cf;
  __syncthreads();
  for (int s = 64; s > 0; s >>= 1) { if (tid < s) red[tid] += red[tid + s]; __syncthreads(); }
  const float vfsum = red[0];
  __syncthreads();
  const float pr = cf / vfsum;
  red[tid] = pr * logf(pr + 1e-10f);
  __syncthreads();
  for (int s = 64; s > 0; s >>= 1) { if (tid < s) red[tid] += red[tid + s]; __syncthreads(); }
  if (tid == 0) {
    const float ent = red[0];
    const float e_latent = ws[SQ_OFF] / (vfsum * (float)NC);
    out[(size_t)BSZ * ZD + 0] = CCF * e_latent;
    out[(size_t)BSZ * ZD + 1] = expf(-ent);
  }
}

// ---------------------------------------------------------------------------
extern "C" void kernel_launch(void* const* d_in, const int* in_sizes, int n_in,
                              void* d_out, int out_size, void* d_ws, size_t ws_size,
                              hipStream_t stream)
{
  const float* fn           = (const float*)d_in[0];
  const unsigned char* mask = (const unsigned char*)d_in[1];
  const float* conv_w       = (const float*)d_in[2];
  const float* conv_b       = (const float*)d_in[3];
  const float* codebook     = (const float*)d_in[4];
  const float* fc_w         = (const float*)d_in[5];
  const float* fc_b         = (const float*)d_in[6];
  const float* mu_w         = (const float*)d_in[7];
  const float* mu_b         = (const float*)d_in[8];
  float* out = (float*)d_out;
  float* ws  = (float*)d_ws;

  hipLaunchKernelGGL(prep1_kernel, dim3(84), dim3(256), 0, stream,
                     codebook, fc_w, fc_b, mu_w, mu_b, ws);
  hipLaunchKernelGGL(prep2_kernel, dim3(1024), dim3(128), 0, stream, codebook, ws);
  hipLaunchKernelGGL(main_kernel, dim3(BSZ / BB), dim3(256), 0, stream,
                     fn, mask, conv_w, conv_b, codebook, ws, out);
  hipLaunchKernelGGL(fin_kernel, dim3(1), dim3(128), 0, stream, ws, out);
}

// Round 7
// 138.861 us; speedup vs baseline: 1.0834x; 1.0834x over previous
//
#include <hip/hip_runtime.h>
#include <math.h>

#define BSZ 65536
#define NC 10
#define T 8
#define NE 128
#define EMB 256
#define ZD 128
#define NCT 80
#define CCF 0.25f
#define BB 32

// ws float offsets
#define WT_OFF  0        // Wt[80][128] fp32, k-major
#define B2_OFF  10240    // 128 fused bias
#define CT_OFF  11904    // 128 u32 histogram
#define SQ_OFF  12032    // 1 float sq-err accumulator
#define AH_OFF  12288    // 2048 floats = 4096 halves: MFMA A-frag table [8][64] half8
#define G_OFF   16384    // G[8][128][128] fp32 gather table (512 KB)

typedef _Float16 half8 __attribute__((ext_vector_type(8)));
typedef float f32x4 __attribute__((ext_vector_type(4)));

// ---------------------------------------------------------------------------
// prep1: Wt = (mu_w@fc_w)^T; b2 = mu_w@fc_b + mu_b; zeros; MFMA A-frag table.
// A-slot layout (K=32): 0-9=-ch, 10-19=-cl, 20-29=-ch, 30=cn/2 hi, 31=cn/2 lo.
// Entry id within a 16-tile: entry = nt*16 + reg*4 + quad, so A row
// m=quad*4+reg holds codebook entry nt*16 + (m&3)*4 + (m>>2).
// ---------------------------------------------------------------------------
__global__ __launch_bounds__(256) void prep1_kernel(
    const float* __restrict__ codebook, const float* __restrict__ fc_w,
    const float* __restrict__ fc_b, const float* __restrict__ mu_w,
    const float* __restrict__ mu_b, float* __restrict__ ws)
{
  const int blk = blockIdx.x, tid = threadIdx.x;
  if (blk < 80) {                       // W = mu_w@fc_w, transposed store
    const int gi = blk * 256 + tid;
    const int idx = gi >> 1, h = gi & 1;
    const int d = idx / NCT, k = idx - d * NCT;
    const float* mw = mu_w + d * EMB + h * 128;
    const float* fw = fc_w + (h * 128) * NCT + k;
    float acc = 0.f;
#pragma unroll 8
    for (int e = 0; e < 128; ++e) acc = fmaf(mw[e], fw[e * NCT], acc);
    acc += __shfl_xor(acc, 1);
    if (h == 0) ws[WT_OFF + k * 128 + d] = acc;
  } else if (blk == 80) {               // b2
    const int d = tid >> 1, h = tid & 1;
    const float* mw = mu_w + d * EMB + h * 128;
    const float* fb = fc_b + h * 128;
    float acc = 0.f;
#pragma unroll 8
    for (int e = 0; e < 128; ++e) acc = fmaf(mw[e], fb[e], acc);
    acc += __shfl_xor(acc, 1);
    if (h == 0) ws[B2_OFF + d] = acc + mu_b[d];
  } else if (blk == 81) {               // zero accumulators
    if (tid < NE) ((unsigned*)ws)[CT_OFF + tid] = 0u;
    if (tid == 0) ws[SQ_OFF] = 0.f;
  } else {                              // blk 82/83: A-frag tables
    const int nt = (blk - 82) * 4 + (tid >> 6);
    const int lane = tid & 63;
    const int rl = lane & 15, q = lane >> 4;
    const int X = nt * 16 + ((rl & 3) << 2) + (rl >> 2);
    float cb_[NC]; float cn = 0.f;
#pragma unroll
    for (int c = 0; c < NC; ++c) { cb_[c] = codebook[X * NC + c]; cn = fmaf(cb_[c], cb_[c], cn); }
    const float cn2 = 0.5f * cn;
    const _Float16 cnh = (_Float16)cn2;
    const _Float16 cnl = (_Float16)(cn2 - (float)cnh);
    half8 hv;
#pragma unroll
    for (int j = 0; j < 8; ++j) {
      const int s = q * 8 + j;
      _Float16 val;
      if (s < 10) {
        val = (_Float16)(-cb_[s]);
      } else if (s < 20) {
        float m = -cb_[s - 10];
        _Float16 mh = (_Float16)m;
        val = (_Float16)(m - (float)mh);
      } else if (s < 30) {
        val = (_Float16)(-cb_[s - 20]);
      } else if (s == 30) val = cnh; else val = cnl;
      hv[j] = val;
    }
    ((half8*)(ws + AH_OFF))[nt * 64 + lane] = hv;
  }
}

// ---------------------------------------------------------------------------
// prep2: G[t][e][d] = sum_c cb[e][c] * W[d][c*8+t]
// ---------------------------------------------------------------------------
__global__ __launch_bounds__(128) void prep2_kernel(
    const float* __restrict__ codebook, float* __restrict__ ws)
{
  const int t = blockIdx.x >> 7, e = blockIdx.x & 127, d = threadIdx.x;
  float acc = 0.f;
#pragma unroll
  for (int c = 0; c < NC; ++c)
    acc = fmaf(codebook[e * NC + c], ws[WT_OFF + (c * 8 + t) * 128 + d], acc);
  ws[G_OFF + ((t * 128 + e) << 7) + d] = acc;
}

// ---------------------------------------------------------------------------
// main: conv -> transposed-MFMA distances -> float-key top-2 (med3 tracker,
// register capture, no kres LDS) -> rare fp64 pair recheck -> G-table gather.
// launch_bounds(256,4): VGPR cap 128 -- NEVER tighter (R6's (256,8) => VGPR 32
// => scratch spills, +48 MB HBM traffic).
// ---------------------------------------------------------------------------
__global__ __launch_bounds__(256, 4) void main_kernel(
    const float* __restrict__ fn, const unsigned char* __restrict__ mask,
    const float* __restrict__ conv_w, const float* __restrict__ conv_b,
    const float* __restrict__ codebook, float* __restrict__ ws,
    float* __restrict__ out)
{
  __shared__ __align__(16) _Float16 zB[4 * 256 * 8];  // [slot_q][pos] half8, 16 KB
  __shared__ unsigned hist[NE];                       // 512 B
  __shared__ float sqacc;

  const int tid = threadIdx.x;
  const int lane = tid & 63, w = tid >> 6;
  const int rl = lane & 15, qd = lane >> 4;

  if (tid < NE) hist[tid] = 0u;
  if (tid == 255) sqacc = 0.f;
  __syncthreads();                      // barrier 1: hist/sqacc ready

  // ---- A-frag preload (global, L2-hot) ----
  const half8* ahp = (const half8*)(ws + AH_OFF);
  half8 A[8];
#pragma unroll
  for (int nt = 0; nt < 8; ++nt) A[nt] = ahp[nt * 64 + lane];

  // ---- conv, one (b,t) per thread ----
  const float4 pv = ((const float4*)fn)[blockIdx.x * 256 + tid];
  float z[NC];
#pragma unroll
  for (int c = 0; c < NC; ++c) {
    float pre = fmaf(pv.w, conv_w[c * 4 + 3], fmaf(pv.z, conv_w[c * 4 + 2],
                fmaf(pv.y, conv_w[c * 4 + 1], fmaf(pv.x, conv_w[c * 4 + 0], conv_b[c]))));
    z[c] = pre > 0.f ? pre : 0.f;
  }
  float zn = 0.f;
#pragma unroll
  for (int c = 0; c < NC; ++c) zn = fmaf(z[c], z[c], zn);
  const float zkey = fmaf(0.5f, zn, 1.0f);   // +1 bias keeps keys positive

  // split z to f16 hi/lo; pack B-vector slots: 0-9=zh, 10-19=zh, 20-29=zl, 30,31=1
  _Float16 zh[NC], zl[NC];
#pragma unroll
  for (int c = 0; c < NC; ++c) {
    zh[c] = (_Float16)z[c];
    zl[c] = (_Float16)(z[c] - (float)zh[c]);
  }
  {
    half8* zb = (half8*)zB;
    zb[0 * 256 + tid] = (half8){zh[0], zh[1], zh[2], zh[3], zh[4], zh[5], zh[6], zh[7]};
    zb[1 * 256 + tid] = (half8){zh[8], zh[9], zh[0], zh[1], zh[2], zh[3], zh[4], zh[5]};
    zb[2 * 256 + tid] = (half8){zh[6], zh[7], zh[8], zh[9], zl[0], zl[1], zl[2], zl[3]};
    zb[3 * 256 + tid] = (half8){zl[4], zl[5], zl[6], zl[7], zl[8], zl[9],
                                (_Float16)1.f, (_Float16)1.f};
  }

  // ---- MFMA distance + float-key top-2 (positive keys: f32 order == u32) ----
  float k1f = 0.f, k2f = 0.f;           // captured at mt == lane>>4
  for (int mt = 0; mt < 4; ++mt) {
    const int pos = mt * 16 + rl;            // wave-relative position
    const int wpos = w * 64 + pos;
    const half8 bf = ((const half8*)zB)[qd * 256 + wpos];
    const float zn2 = __shfl(zkey, pos);     // owner is lane `pos` of this wave
    const f32x4 cinit = {zn2, zn2, zn2, zn2};
    float b1 = 3.4e38f, b2 = 3.4e38f;        // invariant: b1 <= b2
#pragma unroll
    for (int nt = 0; nt < 8; ++nt) {
      const f32x4 acc = __builtin_amdgcn_mfma_f32_16x16x32_f16(A[nt], bf, cinit, 0, 0, 0);
#pragma unroll
      for (int reg = 0; reg < 4; ++reg) {
        const unsigned u = __float_as_uint(acc[reg]);
        const unsigned key = ((u & 0xFFFFFF80u) | (unsigned)qd) + (unsigned)(nt * 16 + reg * 4);
        const float kf = __uint_as_float(key);
        b2 = __builtin_amdgcn_fmed3f(b1, b2, kf);
        b1 = fminf(b1, kf);
      }
    }
#pragma unroll
    for (int s = 16; s <= 32; s <<= 1) {     // merge two sorted pairs across quads
      const float o1 = __shfl_xor(b1, s);
      const float o2 = __shfl_xor(b2, s);
      const float t = fmaxf(b1, o1);
      b1 = fminf(b1, o1);
      b2 = fminf(fminf(b2, o2), t);
    }
    if (mt == (lane >> 4)) { k1f = b1; k2f = b2; }  // lane L == 16*mt + rl holds pos L
  }

  // ---- owner finalize (registers only) ----
  const unsigned kk1 = __float_as_uint(k1f);
  const unsigned kk2 = __float_as_uint(k2f);
  int bi = (int)(kk1 & 127u);
  const float v1 = __uint_as_float(kk1 & 0xFFFFFF80u);
  float vsel = v1;
  {
    const float v2 = __uint_as_float(kk2 & 0xFFFFFF80u);
    if (v2 - v1 < fmaf(1e-4f, v1, 2e-4f)) {  // near-tie: rare fp64 pair recheck
      const int bi2 = (int)(kk2 & 127u);
      double s1 = 0.0, s2 = 0.0;
      for (int c = 0; c < NC; ++c) {
        double a = (double)z[c] - (double)codebook[bi * NC + c];
        double q2 = (double)z[c] - (double)codebook[bi2 * NC + c];
        s1 += a * a; s2 += q2 * q2;
      }
      if (s2 < s1 || (s2 == s1 && bi2 < bi)) { bi = bi2; vsel = v2; }
    }
  }
  // sq err recovered from key: key value = 1 + ||z-c||^2 / 2
  float sq = 2.0f * (vsel - 1.0f);
  sq = sq > 0.f ? sq : 0.f;

  const int bg = blockIdx.x * BB + (tid >> 3);
  const bool valid = (mask[bg] == 0);
  float sv = valid ? sq : 0.f;
#pragma unroll
  for (int off = 32; off > 0; off >>= 1) sv += __shfl_down(sv, off);
  if (lane == 0) atomicAdd(&sqacc, sv);
  if (valid) atomicAdd(&hist[bi], 1u);

  // ---- stage 3: out[b][:] = b2 + sum_t G[t][idx[b,t]][:] (indices via shfl) ----
  const int b_loc = tid >> 3, dc = tid & 7;
  const int obase = lane & ~7;               // wave-relative owner base
  int idx8[8];
#pragma unroll
  for (int t = 0; t < 8; ++t) idx8[t] = __shfl(bi, obase + t);

  float4 a0 = {0, 0, 0, 0}, a1 = {0, 0, 0, 0}, a2 = {0, 0, 0, 0}, a3 = {0, 0, 0, 0};
#pragma unroll
  for (int t = 0; t < 8; ++t) {
    const float4* gp = (const float4*)&ws[G_OFF + ((t * 128 + idx8[t]) << 7)];
    const float4 g0 = gp[0 * 8 + dc], g1 = gp[1 * 8 + dc];
    const float4 g2 = gp[2 * 8 + dc], g3 = gp[3 * 8 + dc];
    a0.x += g0.x; a0.y += g0.y; a0.z += g0.z; a0.w += g0.w;
    a1.x += g1.x; a1.y += g1.y; a1.z += g1.z; a1.w += g1.w;
    a2.x += g2.x; a2.y += g2.y; a2.z += g2.z; a2.w += g2.w;
    a3.x += g3.x; a3.y += g3.y; a3.z += g3.z; a3.w += g3.w;
  }
  {
    const float4* bp = (const float4*)&ws[B2_OFF];
    const float4 b0 = bp[0 * 8 + dc], b1v = bp[1 * 8 + dc];
    const float4 b2v = bp[2 * 8 + dc], b3 = bp[3 * 8 + dc];
    a0.x += b0.x; a0.y += b0.y; a0.z += b0.z; a0.w += b0.w;
    a1.x += b1v.x; a1.y += b1v.y; a1.z += b1v.z; a1.w += b1v.w;
    a2.x += b2v.x; a2.y += b2v.y; a2.z += b2v.z; a2.w += b2v.w;
    a3.x += b3.x; a3.y += b3.y; a3.z += b3.z; a3.w += b3.w;
    float4* op = (float4*)&out[(size_t)(blockIdx.x * BB + b_loc) * ZD];
    op[0 * 8 + dc] = a0; op[1 * 8 + dc] = a1; op[2 * 8 + dc] = a2; op[3 * 8 + dc] = a3;
  }

  // ---- global accumulation ----
  __syncthreads();                      // barrier 2: all atomics done
  if (tid == 0) atomicAdd(&ws[SQ_OFF], sqacc);
  if (tid < NE) { unsigned h = hist[tid]; if (h) atomicAdd(&((unsigned*)ws)[CT_OFF + tid], h); }
}

// ---------------------------------------------------------------------------
// fin: cmt_loss and perplexity.
// ---------------------------------------------------------------------------
__global__ __launch_bounds__(128) void fin_kernel(const float* __restrict__ ws,
                                                  float* __restrict__ out)
{
  __shared__ float red[NE];
  const int tid = threadIdx.x;
  const unsigned c = ((const unsigned*)ws)[CT_OFF + tid];
  const float cf = (float)c;
  red[tid] = cf;
  __syncthreads();
  for (int s = 64; s > 0; s >>= 1) { if (tid < s) red[tid] += red[tid + s]; __syncthreads(); }
  const float vfsum = red[0];
  __syncthreads();
  const float pr = cf / vfsum;
  red[tid] = pr * logf(pr + 1e-10f);
  __syncthreads();
  for (int s = 64; s > 0; s >>= 1) { if (tid < s) red[tid] += red[tid + s]; __syncthreads(); }
  if (tid == 0) {
    const float ent = red[0];
    const float e_latent = ws[SQ_OFF] / (vfsum * (float)NC);
    out[(size_t)BSZ * ZD + 0] = CCF * e_latent;
    out[(size_t)BSZ * ZD + 1] = expf(-ent);
  }
}

// ---------------------------------------------------------------------------
extern "C" void kernel_launch(void* const* d_in, const int* in_sizes, int n_in,
                              void* d_out, int out_size, void* d_ws, size_t ws_size,
                              hipStream_t stream)
{
  const float* fn           = (const float*)d_in[0];
  const unsigned char* mask = (const unsigned char*)d_in[1];
  const float* conv_w       = (const float*)d_in[2];
  const float* conv_b       = (const float*)d_in[3];
  const float* codebook     = (const float*)d_in[4];
  const float* fc_w         = (const float*)d_in[5];
  const float* fc_b         = (const float*)d_in[6];
  const float* mu_w         = (const float*)d_in[7];
  const float* mu_b         = (const float*)d_in[8];
  float* out = (float*)d_out;
  float* ws  = (float*)d_ws;

  hipLaunchKernelGGL(prep1_kernel, dim3(84), dim3(256), 0, stream,
                     codebook, fc_w, fc_b, mu_w, mu_b, ws);
  hipLaunchKernelGGL(prep2_kernel, dim3(1024), dim3(128), 0, stream, codebook, ws);
  hipLaunchKernelGGL(main_kernel, dim3(BSZ / BB), dim3(256), 0, stream,
                     fn, mask, conv_w, conv_b, codebook, ws, out);
  hipLaunchKernelGGL(fin_kernel, dim3(1), dim3(128), 0, stream, ws, out);
}

// Round 8
// 113.801 us; speedup vs baseline: 1.3220x; 1.2202x over previous
//
#include <hip/hip_runtime.h>
#include <math.h>

#define BSZ 65536
#define NC 10
#define T 8
#define NE 128
#define EMB 256
#define ZD 128
#define NCT 80
#define CCF 0.25f
#define BB 32
#define NSH 64       // histogram/sqerr shards (atomic-contention spreader)

// ws dword offsets
#define WT_OFF  0        // Wt[80][128] fp32, k-major
#define B2_OFF  10240    // 128 fused bias
#define AH_OFF  12288    // 2048 floats = 4096 halves: MFMA A-frag table [8][64] half8
#define G_OFF   16384    // G[8][128][128] fp32 gather table (512 KB)
#define CT_SH   147456   // 64 shards x 128 u32 partial histograms (32 KB)
#define SQ_SH   155648   // 64 float sq-err partials

typedef _Float16 half8 __attribute__((ext_vector_type(8)));
typedef float f32x4 __attribute__((ext_vector_type(4)));

// ---------------------------------------------------------------------------
// prep1: Wt = (mu_w@fc_w)^T; b2 = mu_w@fc_b + mu_b; zero shards; A-frag table.
// A-slot layout (K=32): 0-9=-ch, 10-19=-cl, 20-29=-ch, 30=cn/2 hi, 31=cn/2 lo.
// Entry id within a 16-tile: entry = nt*16 + reg*4 + quad.
// ---------------------------------------------------------------------------
__global__ __launch_bounds__(256) void prep1_kernel(
    const float* __restrict__ codebook, const float* __restrict__ fc_w,
    const float* __restrict__ fc_b, const float* __restrict__ mu_w,
    const float* __restrict__ mu_b, float* __restrict__ ws)
{
  const int blk = blockIdx.x, tid = threadIdx.x;
  if (blk < 80) {                       // W = mu_w@fc_w, transposed store
    const int gi = blk * 256 + tid;
    const int idx = gi >> 1, h = gi & 1;
    const int d = idx / NCT, k = idx - d * NCT;
    const float* mw = mu_w + d * EMB + h * 128;
    const float* fw = fc_w + (h * 128) * NCT + k;
    float acc = 0.f;
#pragma unroll 8
    for (int e = 0; e < 128; ++e) acc = fmaf(mw[e], fw[e * NCT], acc);
    acc += __shfl_xor(acc, 1);
    if (h == 0) ws[WT_OFF + k * 128 + d] = acc;
  } else if (blk == 80) {               // b2
    const int d = tid >> 1, h = tid & 1;
    const float* mw = mu_w + d * EMB + h * 128;
    const float* fb = fc_b + h * 128;
    float acc = 0.f;
#pragma unroll 8
    for (int e = 0; e < 128; ++e) acc = fmaf(mw[e], fb[e], acc);
    acc += __shfl_xor(acc, 1);
    if (h == 0) ws[B2_OFF + d] = acc + mu_b[d];
  } else if (blk == 81) {               // zero sharded accumulators
    unsigned* ct = (unsigned*)ws + CT_SH;
    for (int i = tid; i < NSH * NE; i += 256) ct[i] = 0u;
    if (tid < NSH) ws[SQ_SH + tid] = 0.f;
  } else {                              // blk 82/83: A-frag tables
    const int nt = (blk - 82) * 4 + (tid >> 6);
    const int lane = tid & 63;
    const int rl = lane & 15, q = lane >> 4;
    const int X = nt * 16 + ((rl & 3) << 2) + (rl >> 2);
    float cb_[NC]; float cn = 0.f;
#pragma unroll
    for (int c = 0; c < NC; ++c) { cb_[c] = codebook[X * NC + c]; cn = fmaf(cb_[c], cb_[c], cn); }
    const float cn2 = 0.5f * cn;
    const _Float16 cnh = (_Float16)cn2;
    const _Float16 cnl = (_Float16)(cn2 - (float)cnh);
    half8 hv;
#pragma unroll
    for (int j = 0; j < 8; ++j) {
      const int s = q * 8 + j;
      _Float16 val;
      if (s < 10) {
        val = (_Float16)(-cb_[s]);
      } else if (s < 20) {
        float m = -cb_[s - 10];
        _Float16 mh = (_Float16)m;
        val = (_Float16)(m - (float)mh);
      } else if (s < 30) {
        val = (_Float16)(-cb_[s - 20]);
      } else if (s == 30) val = cnh; else val = cnl;
      hv[j] = val;
    }
    ((half8*)(ws + AH_OFF))[nt * 64 + lane] = hv;
  }
}

// ---------------------------------------------------------------------------
// prep2: G[t][e][d] = sum_c cb[e][c] * W[d][c*8+t]
// ---------------------------------------------------------------------------
__global__ __launch_bounds__(128) void prep2_kernel(
    const float* __restrict__ codebook, float* __restrict__ ws)
{
  const int t = blockIdx.x >> 7, e = blockIdx.x & 127, d = threadIdx.x;
  float acc = 0.f;
#pragma unroll
  for (int c = 0; c < NC; ++c)
    acc = fmaf(codebook[e * NC + c], ws[WT_OFF + (c * 8 + t) * 128 + d], acc);
  ws[G_OFF + ((t * 128 + e) << 7) + d] = acc;
}

// ---------------------------------------------------------------------------
// main: conv -> transposed-MFMA distances -> float-key top-2 (med3 tracker,
// register capture) -> rare fp64 pair recheck -> G-table gather.
// launch_bounds(256,4): VGPR cap 128 -- NEVER tighter (R6: (256,8) => spills).
// Histogram/sqerr flush goes to shard (blockIdx&63) -- R7 showed a ~50 us
// floor from all blocks' atomics hammering the same 4-5 cache lines.
// ---------------------------------------------------------------------------
__global__ __launch_bounds__(256, 4) void main_kernel(
    const float* __restrict__ fn, const unsigned char* __restrict__ mask,
    const float* __restrict__ conv_w, const float* __restrict__ conv_b,
    const float* __restrict__ codebook, float* __restrict__ ws,
    float* __restrict__ out)
{
  __shared__ __align__(16) _Float16 zB[4 * 256 * 8];  // [slot_q][pos] half8, 16 KB
  __shared__ unsigned hist[NE];                       // 512 B
  __shared__ float sqacc;

  const int tid = threadIdx.x;
  const int lane = tid & 63, w = tid >> 6;
  const int rl = lane & 15, qd = lane >> 4;

  if (tid < NE) hist[tid] = 0u;
  if (tid == 255) sqacc = 0.f;
  __syncthreads();                      // barrier 1: hist/sqacc ready

  // ---- A-frag preload (global, L2-hot) ----
  const half8* ahp = (const half8*)(ws + AH_OFF);
  half8 A[8];
#pragma unroll
  for (int nt = 0; nt < 8; ++nt) A[nt] = ahp[nt * 64 + lane];

  // ---- conv, one (b,t) per thread ----
  const float4 pv = ((const float4*)fn)[blockIdx.x * 256 + tid];
  float z[NC];
#pragma unroll
  for (int c = 0; c < NC; ++c) {
    float pre = fmaf(pv.w, conv_w[c * 4 + 3], fmaf(pv.z, conv_w[c * 4 + 2],
                fmaf(pv.y, conv_w[c * 4 + 1], fmaf(pv.x, conv_w[c * 4 + 0], conv_b[c]))));
    z[c] = pre > 0.f ? pre : 0.f;
  }
  float zn = 0.f;
#pragma unroll
  for (int c = 0; c < NC; ++c) zn = fmaf(z[c], z[c], zn);
  const float zkey = fmaf(0.5f, zn, 1.0f);   // +1 bias keeps keys positive

  // split z to f16 hi/lo; pack B-vector slots: 0-9=zh, 10-19=zh, 20-29=zl, 30,31=1
  _Float16 zh[NC], zl[NC];
#pragma unroll
  for (int c = 0; c < NC; ++c) {
    zh[c] = (_Float16)z[c];
    zl[c] = (_Float16)(z[c] - (float)zh[c]);
  }
  {
    half8* zb = (half8*)zB;
    zb[0 * 256 + tid] = (half8){zh[0], zh[1], zh[2], zh[3], zh[4], zh[5], zh[6], zh[7]};
    zb[1 * 256 + tid] = (half8){zh[8], zh[9], zh[0], zh[1], zh[2], zh[3], zh[4], zh[5]};
    zb[2 * 256 + tid] = (half8){zh[6], zh[7], zh[8], zh[9], zl[0], zl[1], zl[2], zl[3]};
    zb[3 * 256 + tid] = (half8){zl[4], zl[5], zl[6], zl[7], zl[8], zl[9],
                                (_Float16)1.f, (_Float16)1.f};
  }

  // ---- MFMA distance + float-key top-2 (positive keys: f32 order == u32) ----
  float k1f = 0.f, k2f = 0.f;           // captured at mt == lane>>4
  for (int mt = 0; mt < 4; ++mt) {
    const int pos = mt * 16 + rl;            // wave-relative position
    const int wpos = w * 64 + pos;
    const half8 bf = ((const half8*)zB)[qd * 256 + wpos];
    const float zn2 = __shfl(zkey, pos);     // owner is lane `pos` of this wave
    const f32x4 cinit = {zn2, zn2, zn2, zn2};
    float b1 = 3.4e38f, b2 = 3.4e38f;        // invariant: b1 <= b2
#pragma unroll
    for (int nt = 0; nt < 8; ++nt) {
      const f32x4 acc = __builtin_amdgcn_mfma_f32_16x16x32_f16(A[nt], bf, cinit, 0, 0, 0);
#pragma unroll
      for (int reg = 0; reg < 4; ++reg) {
        const unsigned u = __float_as_uint(acc[reg]);
        const unsigned key = ((u & 0xFFFFFF80u) | (unsigned)qd) + (unsigned)(nt * 16 + reg * 4);
        const float kf = __uint_as_float(key);
        b2 = __builtin_amdgcn_fmed3f(b1, b2, kf);
        b1 = fminf(b1, kf);
      }
    }
#pragma unroll
    for (int s = 16; s <= 32; s <<= 1) {     // merge two sorted pairs across quads
      const float o1 = __shfl_xor(b1, s);
      const float o2 = __shfl_xor(b2, s);
      const float t = fmaxf(b1, o1);
      b1 = fminf(b1, o1);
      b2 = fminf(fminf(b2, o2), t);
    }
    if (mt == (lane >> 4)) { k1f = b1; k2f = b2; }  // lane L == 16*mt + rl holds pos L
  }

  // ---- owner finalize (registers only) ----
  const unsigned kk1 = __float_as_uint(k1f);
  const unsigned kk2 = __float_as_uint(k2f);
  int bi = (int)(kk1 & 127u);
  const float v1 = __uint_as_float(kk1 & 0xFFFFFF80u);
  float vsel = v1;
  {
    const float v2 = __uint_as_float(kk2 & 0xFFFFFF80u);
    if (v2 - v1 < fmaf(1e-4f, v1, 2e-4f)) {  // near-tie: rare fp64 pair recheck
      const int bi2 = (int)(kk2 & 127u);
      double s1 = 0.0, s2 = 0.0;
      for (int c = 0; c < NC; ++c) {
        double a = (double)z[c] - (double)codebook[bi * NC + c];
        double q2 = (double)z[c] - (double)codebook[bi2 * NC + c];
        s1 += a * a; s2 += q2 * q2;
      }
      if (s2 < s1 || (s2 == s1 && bi2 < bi)) { bi = bi2; vsel = v2; }
    }
  }
  // sq err recovered from key: key value = 1 + ||z-c||^2 / 2
  float sq = 2.0f * (vsel - 1.0f);
  sq = sq > 0.f ? sq : 0.f;

  const int bg = blockIdx.x * BB + (tid >> 3);
  const bool valid = (mask[bg] == 0);
  float sv = valid ? sq : 0.f;
#pragma unroll
  for (int off = 32; off > 0; off >>= 1) sv += __shfl_down(sv, off);
  if (lane == 0) atomicAdd(&sqacc, sv);
  if (valid) atomicAdd(&hist[bi], 1u);

  // ---- stage 3: out[b][:] = b2 + sum_t G[t][idx[b,t]][:] (indices via shfl) ----
  const int b_loc = tid >> 3, dc = tid & 7;
  const int obase = lane & ~7;               // wave-relative owner base
  int idx8[8];
#pragma unroll
  for (int t = 0; t < 8; ++t) idx8[t] = __shfl(bi, obase + t);

  float4 a0 = {0, 0, 0, 0}, a1 = {0, 0, 0, 0}, a2 = {0, 0, 0, 0}, a3 = {0, 0, 0, 0};
#pragma unroll
  for (int t = 0; t < 8; ++t) {
    const float4* gp = (const float4*)&ws[G_OFF + ((t * 128 + idx8[t]) << 7)];
    const float4 g0 = gp[0 * 8 + dc], g1 = gp[1 * 8 + dc];
    const float4 g2 = gp[2 * 8 + dc], g3 = gp[3 * 8 + dc];
    a0.x += g0.x; a0.y += g0.y; a0.z += g0.z; a0.w += g0.w;
    a1.x += g1.x; a1.y += g1.y; a1.z += g1.z; a1.w += g1.w;
    a2.x += g2.x; a2.y += g2.y; a2.z += g2.z; a2.w += g2.w;
    a3.x += g3.x; a3.y += g3.y; a3.z += g3.z; a3.w += g3.w;
  }
  {
    const float4* bp = (const float4*)&ws[B2_OFF];
    const float4 b0 = bp[0 * 8 + dc], b1v = bp[1 * 8 + dc];
    const float4 b2v = bp[2 * 8 + dc], b3 = bp[3 * 8 + dc];
    a0.x += b0.x; a0.y += b0.y; a0.z += b0.z; a0.w += b0.w;
    a1.x += b1v.x; a1.y += b1v.y; a1.z += b1v.z; a1.w += b1v.w;
    a2.x += b2v.x; a2.y += b2v.y; a2.z += b2v.z; a2.w += b2v.w;
    a3.x += b3.x; a3.y += b3.y; a3.z += b3.z; a3.w += b3.w;
    float4* op = (float4*)&out[(size_t)(blockIdx.x * BB + b_loc) * ZD];
    op[0 * 8 + dc] = a0; op[1 * 8 + dc] = a1; op[2 * 8 + dc] = a2; op[3 * 8 + dc] = a3;
  }

  // ---- sharded global accumulation (contention / 64) ----
  __syncthreads();                      // barrier 2: all LDS atomics done
  const int sh = blockIdx.x & (NSH - 1);
  if (tid == 0) atomicAdd(&ws[SQ_SH + sh], sqacc);
  if (tid < NE) {
    unsigned h = hist[tid];
    if (h) atomicAdd(&((unsigned*)ws)[CT_SH + sh * NE + tid], h);
  }
}

// ---------------------------------------------------------------------------
// fin: reduce shards -> cmt_loss and perplexity.
// ---------------------------------------------------------------------------
__global__ __launch_bounds__(128) void fin_kernel(const float* __restrict__ ws,
                                                  float* __restrict__ out)
{
  __shared__ float red[NE];
  __shared__ float sqtot;
  const int tid = threadIdx.x;

  // sum this entry's count over all shards
  unsigned cu = 0u;
  const unsigned* ct = (const unsigned*)ws + CT_SH;
#pragma unroll 8
  for (int s = 0; s < NSH; ++s) cu += ct[s * NE + tid];
  const float cf = (float)cu;

  // sum sq-err shards (first wave)
  if (tid < 64) {
    float v = ws[SQ_SH + tid];
#pragma unroll
    for (int off = 32; off > 0; off >>= 1) v += __shfl_down(v, off);
    if (tid == 0) sqtot = v;
  }

  red[tid] = cf;
  __syncthreads();
  for (int s = 64; s > 0; s >>= 1) { if (tid < s) red[tid] += red[tid + s]; __syncthreads(); }
  const float vfsum = red[0];
  __syncthreads();
  const float pr = cf / vfsum;
  red[tid] = pr * logf(pr + 1e-10f);
  __syncthreads();
  for (int s = 64; s > 0; s >>= 1) { if (tid < s) red[tid] += red[tid + s]; __syncthreads(); }
  if (tid == 0) {
    const float ent = red[0];
    const float e_latent = sqtot / (vfsum * (float)NC);
    out[(size_t)BSZ * ZD + 0] = CCF * e_latent;
    out[(size_t)BSZ * ZD + 1] = expf(-ent);
  }
}

// ---------------------------------------------------------------------------
extern "C" void kernel_launch(void* const* d_in, const int* in_sizes, int n_in,
                              void* d_out, int out_size, void* d_ws, size_t ws_size,
                              hipStream_t stream)
{
  const float* fn           = (const float*)d_in[0];
  const unsigned char* mask = (const unsigned char*)d_in[1];
  const float* conv_w       = (const float*)d_in[2];
  const float* conv_b       = (const float*)d_in[3];
  const float* codebook     = (const float*)d_in[4];
  const float* fc_w         = (const float*)d_in[5];
  const float* fc_b         = (const float*)d_in[6];
  const float* mu_w         = (const float*)d_in[7];
  const float* mu_b         = (const float*)d_in[8];
  float* out = (float*)d_out;
  float* ws  = (float*)d_ws;

  hipLaunchKernelGGL(prep1_kernel, dim3(84), dim3(256), 0, stream,
                     codebook, fc_w, fc_b, mu_w, mu_b, ws);
  hipLaunchKernelGGL(prep2_kernel, dim3(1024), dim3(128), 0, stream, codebook, ws);
  hipLaunchKernelGGL(main_kernel, dim3(BSZ / BB), dim3(256), 0, stream,
                     fn, mask, conv_w, conv_b, codebook, ws, out);
  hipLaunchKernelGGL(fin_kernel, dim3(1), dim3(128), 0, stream, ws, out);
}